// Round 3
// baseline (813.492 us; speedup 1.0000x reference)
//
#include <hip/hip_runtime.h>
#include <hip/hip_bf16.h>

#define HIDDIM 128

// ---------------- degree count (4 edges/thread, int4 loads, ILP on atomics) --
__global__ void k_count(const int* __restrict__ ei, int* __restrict__ cnt, int E) {
    int e0 = (blockIdx.x * 256 + threadIdx.x) * 4;
    if (e0 + 3 < E && (E & 3) == 0) {
        int4 d4 = *(const int4*)&ei[E + e0];
        atomicAdd(&cnt[d4.x], 1);
        atomicAdd(&cnt[d4.y], 1);
        atomicAdd(&cnt[d4.z], 1);
        atomicAdd(&cnt[d4.w], 1);
    } else {
        for (int e = e0; e < min(e0 + 4, E); ++e) atomicAdd(&cnt[ei[E + e]], 1);
    }
}

__global__ void k_dinv(const int* __restrict__ cnt, float* __restrict__ dinv, int n) {
    int i = blockIdx.x * 256 + threadIdx.x;
    if (i < n) dinv[i] = rsqrtf((float)cnt[i] + 1.0f);
}

// ---------------- exclusive scan (3-kernel hierarchical) ----------------
__global__ void k_scan1(const int* __restrict__ cnt, int* __restrict__ row_off,
                        int* __restrict__ bsums, int n) {
    __shared__ int sh[256];
    int t = threadIdx.x;
    int base = blockIdx.x * 1024 + t * 4;
    int v0 = 0, v1 = 0, v2 = 0, v3 = 0;
    if (base + 0 < n) v0 = cnt[base + 0];
    if (base + 1 < n) v1 = cnt[base + 1];
    if (base + 2 < n) v2 = cnt[base + 2];
    if (base + 3 < n) v3 = cnt[base + 3];
    int s = v0 + v1 + v2 + v3;
    sh[t] = s;
    __syncthreads();
    for (int off = 1; off < 256; off <<= 1) {
        int x = (t >= off) ? sh[t - off] : 0;
        __syncthreads();
        sh[t] += x;
        __syncthreads();
    }
    int excl = sh[t] - s;
    int r0 = excl + v0, r1 = r0 + v1, r2 = r1 + v2, r3 = r2 + v3;
    if (base + 0 < n) row_off[base + 1] = r0;
    if (base + 1 < n) row_off[base + 2] = r1;
    if (base + 2 < n) row_off[base + 3] = r2;
    if (base + 3 < n) row_off[base + 4] = r3;
    if (t == 255) bsums[blockIdx.x] = sh[255];
}

__global__ void k_scan2(int* bsums, int nb) {
    if (threadIdx.x == 0 && blockIdx.x == 0) {
        int run = 0;
        for (int i = 0; i < nb; ++i) { int v = bsums[i]; bsums[i] = run; run += v; }
    }
}

// also materializes cursor = final row_off (absolute slot counters for k_fill)
__global__ void k_scan3(int* __restrict__ row_off, int* __restrict__ cursor,
                        const int* __restrict__ bsums, int n) {
    int i = blockIdx.x * 256 + threadIdx.x;
    if (i == 0) { row_off[0] = 0; cursor[0] = 0; }
    if (i < n) {
        int v = row_off[i + 1] + bsums[i >> 10];
        row_off[i + 1] = v;
        cursor[i + 1] = v;
    }
}

// ---------------- CSR fill: packed (src, norm) int2, 4 edges/thread ---------
__global__ void k_fill(const int* __restrict__ ei, int* __restrict__ cursor,
                       const float* __restrict__ dinv, int2* __restrict__ csr, int E) {
    int e0 = (blockIdx.x * 256 + threadIdx.x) * 4;
    if (e0 + 3 < E && (E & 3) == 0) {
        int4 s4 = *(const int4*)&ei[e0];
        int4 d4 = *(const int4*)&ei[E + e0];
        float n0 = dinv[s4.x] * dinv[d4.x];
        float n1 = dinv[s4.y] * dinv[d4.y];
        float n2 = dinv[s4.z] * dinv[d4.z];
        float n3 = dinv[s4.w] * dinv[d4.w];
        int p0 = atomicAdd(&cursor[d4.x], 1);
        int p1 = atomicAdd(&cursor[d4.y], 1);
        int p2 = atomicAdd(&cursor[d4.z], 1);
        int p3 = atomicAdd(&cursor[d4.w], 1);
        csr[p0] = make_int2(s4.x, __float_as_int(n0));
        csr[p1] = make_int2(s4.y, __float_as_int(n1));
        csr[p2] = make_int2(s4.z, __float_as_int(n2));
        csr[p3] = make_int2(s4.w, __float_as_int(n3));
    } else {
        for (int e = e0; e < min(e0 + 4, E); ++e) {
            int s = ei[e], d = ei[E + e];
            int p = atomicAdd(&cursor[d], 1);
            csr[p] = make_int2(s, __float_as_int(dinv[s] * dinv[d]));
        }
    }
}

// ---------------- GEMM: [N,128] @ [128,128] -> [N,128], fp32 ----------------
__global__ __launch_bounds__(256) void k_gemm(const float* __restrict__ A,
                                              const float* __restrict__ W,
                                              float* __restrict__ O, int nrows) {
    __shared__ float sW[64 * 128];  // 32 KB
    __shared__ float sA[32 * 128];  // 16 KB
    int t = threadIdx.x;
    int row0 = blockIdx.x * 32;
    {
        int kc = t & 31, rq = t >> 5;
        float4* sA4 = (float4*)sA;
#pragma unroll
        for (int rr = 0; rr < 4; ++rr) {
            int r = rq + rr * 8;
            int gr = row0 + r;
            float4 v = make_float4(0.f, 0.f, 0.f, 0.f);
            if (gr < nrows) v = *(const float4*)(A + (size_t)gr * 128 + kc * 4);
            sA4[r * 32 + kc] = v;
        }
    }
    int c4 = (t & 31) * 4;
    int r4 = (t >> 5) * 4;
    float acc[4][4];
#pragma unroll
    for (int i = 0; i < 4; ++i)
#pragma unroll
        for (int j = 0; j < 4; ++j) acc[i][j] = 0.f;

    for (int half = 0; half < 2; ++half) {
        __syncthreads();
        {
            const float4* W4 = (const float4*)(W + half * 64 * 128);
            float4* sW4 = (float4*)sW;
#pragma unroll
            for (int i = 0; i < 8; ++i) sW4[t + 256 * i] = W4[t + 256 * i];
        }
        __syncthreads();
#pragma unroll 2
        for (int k = 0; k < 64; k += 4) {
            float4 w0 = *(const float4*)&sW[(k + 0) * 128 + c4];
            float4 w1 = *(const float4*)&sW[(k + 1) * 128 + c4];
            float4 w2 = *(const float4*)&sW[(k + 2) * 128 + c4];
            float4 w3 = *(const float4*)&sW[(k + 3) * 128 + c4];
#pragma unroll
            for (int i = 0; i < 4; ++i) {
                float4 a = *(const float4*)&sA[(r4 + i) * 128 + half * 64 + k];
                acc[i][0] = fmaf(a.x, w0.x, acc[i][0]);
                acc[i][1] = fmaf(a.x, w0.y, acc[i][1]);
                acc[i][2] = fmaf(a.x, w0.z, acc[i][2]);
                acc[i][3] = fmaf(a.x, w0.w, acc[i][3]);
                acc[i][0] = fmaf(a.y, w1.x, acc[i][0]);
                acc[i][1] = fmaf(a.y, w1.y, acc[i][1]);
                acc[i][2] = fmaf(a.y, w1.z, acc[i][2]);
                acc[i][3] = fmaf(a.y, w1.w, acc[i][3]);
                acc[i][0] = fmaf(a.z, w2.x, acc[i][0]);
                acc[i][1] = fmaf(a.z, w2.y, acc[i][1]);
                acc[i][2] = fmaf(a.z, w2.z, acc[i][2]);
                acc[i][3] = fmaf(a.z, w2.w, acc[i][3]);
                acc[i][0] = fmaf(a.w, w3.x, acc[i][0]);
                acc[i][1] = fmaf(a.w, w3.y, acc[i][1]);
                acc[i][2] = fmaf(a.w, w3.z, acc[i][2]);
                acc[i][3] = fmaf(a.w, w3.w, acc[i][3]);
            }
        }
    }
#pragma unroll
    for (int i = 0; i < 4; ++i) {
        int gr = row0 + r4 + i;
        if (gr < nrows) {
            float4 o;
            o.x = acc[i][0]; o.y = acc[i][1]; o.z = acc[i][2]; o.w = acc[i][3];
            *(float4*)(O + (size_t)gr * 128 + c4) = o;
        }
    }
}

// ---------------- aggregation: agg = sum norm*h[src] + dinv^2*h[self]; relu(+b) ----
// one wave per node; lane holds cols {2*lane, 2*lane+1}. 8 edges in flight,
// packed int2 CSR (one 8B load per edge instead of two 4B loads).
__global__ __launch_bounds__(256) void k_agg(const float* __restrict__ h,
                                             const int* __restrict__ row_off,
                                             const int2* __restrict__ csr,
                                             const float* __restrict__ dinv,
                                             const float* __restrict__ bias,
                                             float* __restrict__ out, int n) {
    int node = blockIdx.x * 4 + (threadIdx.x >> 6);
    int lane = threadIdx.x & 63;
    if (node >= n) return;
    float d = dinv[node];
    float d2 = d * d;
    const float2* __restrict__ h2 = (const float2*)h;
    float2 self = h2[(size_t)node * 64 + lane];
    float acc0 = self.x * d2;
    float acc1 = self.y * d2;
    int s = row_off[node], e = row_off[node + 1];
    for (int t = s; t < e; t += 8) {
        int2 c[8];
#pragma unroll
        for (int j = 0; j < 8; ++j) {
            int tt = t + j;
            bool ok = tt < e;
            c[j] = csr[ok ? tt : s];
            if (!ok) c[j].y = 0;  // norm = 0.0f
        }
        float2 v[8];
#pragma unroll
        for (int j = 0; j < 8; ++j) v[j] = h2[(size_t)c[j].x * 64 + lane];
#pragma unroll
        for (int j = 0; j < 8; ++j) {
            float nm = __int_as_float(c[j].y);
            acc0 = fmaf(nm, v[j].x, acc0);
            acc1 = fmaf(nm, v[j].y, acc1);
        }
    }
    float2 b2 = ((const float2*)bias)[lane];
    float2 o;
    o.x = fmaxf(acc0 + b2.x, 0.f);
    o.y = fmaxf(acc1 + b2.y, 0.f);
    ((float2*)out)[(size_t)node * 64 + lane] = o;
}

// ---------------- pooling (batch sorted -> segment runs, few atomics) --------
__global__ void k_pool(const float* __restrict__ h, const int* __restrict__ batch,
                       float* __restrict__ gsum, float* __restrict__ gmax,
                       int* __restrict__ gcnt, int n) {
    int t = threadIdx.x;  // 128
    int start = blockIdx.x * 64;
    if (start >= n) return;
    int end = min(start + 64, n);
    int cur = batch[start];
    float s = 0.f, m = 0.f;
    int c = 0;
    for (int i = start; i < end; ++i) {
        int g = batch[i];
        if (g != cur) {
            atomicAdd(&gsum[cur * 128 + t], s);
            atomicMax((int*)&gmax[cur * 128 + t], __float_as_int(m));
            if (t == 0) atomicAdd(&gcnt[cur], c);
            s = 0.f; m = 0.f; c = 0; cur = g;
        }
        float v = h[(size_t)i * 128 + t];
        s += v;
        m = fmaxf(m, v);
        c++;
    }
    atomicAdd(&gsum[cur * 128 + t], s);
    atomicMax((int*)&gmax[cur * 128 + t], __float_as_int(m));  // h >= 0 post-relu
    if (t == 0) atomicAdd(&gcnt[cur], c);
}

// ---------------- MLP head, one block per graph ----------------
__global__ void k_head(const float* __restrict__ gsum, const float* __restrict__ gmax,
                       const int* __restrict__ gcnt, const float* __restrict__ Wc1,
                       const float* __restrict__ bc1, const float* __restrict__ Wc2,
                       const float* __restrict__ bc2, float* __restrict__ out, int G) {
    __shared__ float gv[256];
    __shared__ float hc[128];
    int g = blockIdx.x;
    if (g >= G) return;
    int t = threadIdx.x;  // 128
    float c = (float)gcnt[g];
    float inv = 1.0f / fmaxf(c, 1.0f);
    gv[t] = gsum[g * 128 + t] * inv;
    gv[128 + t] = gmax[g * 128 + t];
    __syncthreads();
    float a = bc1[t];
#pragma unroll 8
    for (int k = 0; k < 256; ++k) a = fmaf(gv[k], Wc1[k * 128 + t], a);
    hc[t] = fmaxf(a, 0.f);
    __syncthreads();
    if (t < 10) {
        float o = bc2[t];
        for (int k = 0; k < 128; ++k) o = fmaf(hc[k], Wc2[k * 10 + t], o);
        out[g * 10 + t] = o;
    }
}

extern "C" void kernel_launch(void* const* d_in, const int* in_sizes, int n_in,
                              void* d_out, int out_size, void* d_ws, size_t ws_size,
                              hipStream_t stream) {
    const float* x   = (const float*)d_in[0];
    const int*   ei  = (const int*)d_in[1];
    const int*   bat = (const int*)d_in[2];
    const float* W1  = (const float*)d_in[3];
    const float* b1  = (const float*)d_in[4];
    const float* W2  = (const float*)d_in[5];
    const float* b2  = (const float*)d_in[6];
    const float* W3  = (const float*)d_in[7];
    const float* b3  = (const float*)d_in[8];
    const float* Wc1 = (const float*)d_in[9];
    const float* bc1 = (const float*)d_in[10];
    const float* Wc2 = (const float*)d_in[11];
    const float* bc2 = (const float*)d_in[12];
    float* out = (float*)d_out;

    const int N = in_sizes[0] / HIDDIM;  // 100000
    const int E = in_sizes[1] / 2;       // 1600000
    const int G = out_size / 10;         // 512

    char* ws = (char*)d_ws;
    size_t off = 0;
    auto take = [&](size_t bytes) -> char* {
        char* p = ws + off;
        off += (bytes + 255) & ~(size_t)255;
        return p;
    };
    float* hA       = (float*)take((size_t)N * HIDDIM * 4);
    float* hB       = (float*)take((size_t)N * HIDDIM * 4);
    float* dinv     = (float*)take((size_t)N * 4);
    int*   cnt      = (int*)take((size_t)N * 4);
    int*   row_off  = (int*)take(((size_t)N + 1) * 4);
    int*   cursor   = (int*)take(((size_t)N + 1) * 4);
    int*   bsums    = (int*)take(1024 * 4);
    int2*  csr      = (int2*)take((size_t)E * 8);
    float* gsum     = (float*)take((size_t)G * HIDDIM * 4);
    float* gmax     = (float*)take((size_t)G * HIDDIM * 4);
    int*   gcnt     = (int*)take((size_t)G * 4);

    hipMemsetAsync(cnt, 0, (size_t)N * 4, stream);
    hipMemsetAsync(gsum, 0, (size_t)G * HIDDIM * 4, stream);
    hipMemsetAsync(gmax, 0, (size_t)G * HIDDIM * 4, stream);
    hipMemsetAsync(gcnt, 0, (size_t)G * 4, stream);

    int e4b = (E / 4 + 255) / 256 + 1;  // 4 edges/thread grids (guarded)
    int nb = (N + 1023) / 1024;
    k_count<<<e4b, 256, 0, stream>>>(ei, cnt, E);
    k_dinv<<<(N + 255) / 256, 256, 0, stream>>>(cnt, dinv, N);
    k_scan1<<<nb, 256, 0, stream>>>(cnt, row_off, bsums, N);
    k_scan2<<<1, 64, 0, stream>>>(bsums, nb);
    k_scan3<<<(N + 255) / 256, 256, 0, stream>>>(row_off, cursor, bsums, N);
    k_fill<<<e4b, 256, 0, stream>>>(ei, cursor, dinv, csr, E);

    int gb = (N + 31) / 32;
    int ab = (N + 3) / 4;
    k_gemm<<<gb, 256, 0, stream>>>(x, W1, hB, N);
    k_agg<<<ab, 256, 0, stream>>>(hB, row_off, csr, dinv, b1, hA, N);
    k_gemm<<<gb, 256, 0, stream>>>(hA, W2, hB, N);
    k_agg<<<ab, 256, 0, stream>>>(hB, row_off, csr, dinv, b2, hA, N);
    k_gemm<<<gb, 256, 0, stream>>>(hA, W3, hB, N);
    k_agg<<<ab, 256, 0, stream>>>(hB, row_off, csr, dinv, b3, hA, N);

    k_pool<<<(N + 63) / 64, 128, 0, stream>>>(hA, bat, gsum, gmax, gcnt, N);
    k_head<<<G, 128, 0, stream>>>(gsum, gmax, gcnt, Wc1, bc1, Wc2, bc2, out, G);
}

// Round 4
// 618.434 us; speedup vs baseline: 1.3154x; 1.3154x over previous
//
#include <hip/hip_runtime.h>
#include <hip/hip_bf16.h>

#define HIDDIM 128
#define NABLK 256      // phase-A blocks
#define EPB 6250       // edges per phase-A block (E = 1.6M / 256)
#define BCAP 5120      // phase-B LDS edge capacity (mean 4096, +16 sigma)

// ---------- inclusive scan of 256 values across 256 threads ----------
__device__ __forceinline__ int scan256_incl(int v, int* sbuf, int t) {
    sbuf[t] = v;
    __syncthreads();
    for (int off = 1; off < 256; off <<= 1) {
        int x = sbuf[t];
        if (t >= off) x += sbuf[t - off];
        __syncthreads();
        sbuf[t] = x;
        __syncthreads();
    }
    return sbuf[t];
}

// ---------- phase A: per-block bucket sort of edges (bucket = dst>>8) ------
// Writes sortedA (block-contiguous, bucket-sorted within block) and
// tableA[b][blk] = exclusive base of bucket b within block blk (row nbuck = total).
__global__ __launch_bounds__(1024) void k_bucketA(const int* __restrict__ ei, int E,
                                                  int2* __restrict__ sortedA,
                                                  int* __restrict__ tableA, int nbuck) {
    __shared__ int2 sEdge[EPB];   // 50 KB
    __shared__ int hist[512];
    __shared__ int sb[512];
    int t = threadIdx.x;
    int blk = blockIdx.x;
    int base = blk * EPB;
    int cnt = min(EPB, E - base);
    if (t < 512) hist[t] = 0;
    __syncthreads();
    int es[7], ed[7], rk[7];
#pragma unroll
    for (int it = 0; it < 7; ++it) {
        int i = it * 1024 + t;
        es[it] = 0; ed[it] = -1; rk[it] = 0;
        if (i < cnt) {
            es[it] = ei[base + i];
            ed[it] = ei[E + base + i];
            rk[it] = atomicAdd(&hist[ed[it] >> 8], 1);   // LDS atomic: count + rank
        }
    }
    __syncthreads();
    // inclusive scan of hist -> sb
    if (t < 512) sb[t] = hist[t];
    __syncthreads();
    for (int off = 1; off < 512; off <<= 1) {
        int x = 0;
        if (t < 512) { x = sb[t]; if (t >= off) x += sb[t - off]; }
        __syncthreads();
        if (t < 512) sb[t] = x;
        __syncthreads();
    }
    // scatter into bucket-sorted LDS positions
#pragma unroll
    for (int it = 0; it < 7; ++it) {
        if (ed[it] >= 0) {
            int b = ed[it] >> 8;
            int slot = sb[b] - hist[b] + rk[it];   // excl base + rank
            sEdge[slot] = make_int2(es[it], ed[it]);
        }
    }
    if (t <= nbuck) tableA[t * NABLK + blk] = sb[t] - hist[t];  // excl bases
    __syncthreads();
    // dense coalesced write-out
    for (int j = t; j < cnt; j += 1024) sortedA[base + j] = sEdge[j];
}

// ---------- per-bucket totals: tot[b] = sum over blocks of run lengths -----
__global__ void k_btot(const int* __restrict__ tableA, int* __restrict__ tot) {
    __shared__ int red[4];
    int b = blockIdx.x;
    int t = threadIdx.x;  // 256
    int v = tableA[(b + 1) * NABLK + t] - tableA[b * NABLK + t];
    for (int off = 32; off; off >>= 1) v += __shfl_down(v, off, 64);
    if ((t & 63) == 0) red[t >> 6] = v;
    __syncthreads();
    if (t == 0) tot[b] = red[0] + red[1] + red[2] + red[3];
}

// ---------- bbase = exclusive scan of tot ----------
__global__ void k_bbase(const int* __restrict__ tot, int* __restrict__ bbase, int nbuck) {
    __shared__ int sb[512];
    int t = threadIdx.x;  // 512
    int v = (t < nbuck) ? tot[t] : 0;
    sb[t] = v;
    __syncthreads();
    for (int off = 1; off < 512; off <<= 1) {
        int x = sb[t];
        if (t >= off) x += sb[t - off];
        __syncthreads();
        sb[t] = x;
        __syncthreads();
    }
    if (t < nbuck) bbase[t] = sb[t] - v;
}

// ---------- phase B: per-bucket exact CSR build (256 nodes per bucket) -----
__global__ __launch_bounds__(256) void k_bucketB(const int2* __restrict__ sortedA,
                                                 const int* __restrict__ tableA,
                                                 const int* __restrict__ bbase,
                                                 int* __restrict__ csr_src,
                                                 int* __restrict__ row_off,
                                                 float* __restrict__ dinv, int N) {
    __shared__ int2 eIn[BCAP];     // 40 KB
    __shared__ int h[256];
    __shared__ int cur[256];
    __shared__ int scanbuf[256];
    int b = blockIdx.x;
    int t = threadIdx.x;  // source-block index
    int s = tableA[b * NABLK + t];
    int c = tableA[(b + 1) * NABLK + t] - s;
    int rIncl = scan256_incl(c, scanbuf, t);
    int rOff = rIncl - c;
    int nE = scanbuf[255];
    // gather this bucket's runs from every phase-A block segment
    for (int k = 0; k < c; ++k) {
        int p = rOff + k;
        if (p < BCAP) eIn[p] = sortedA[t * EPB + s + k];
    }
    h[t] = 0;
    __syncthreads();
    if (nE > BCAP) nE = BCAP;  // defensive (never expected)
    for (int j = t; j < nE; j += 256) atomicAdd(&h[eIn[j].y & 255], 1);
    __syncthreads();
    int deg = h[t];
    int nIncl = scan256_incl(deg, scanbuf, t);
    int nOff = nIncl - deg;
    int g = b * 256 + t;
    int bb = bbase[b];
    if (g < N) {
        dinv[g] = rsqrtf((float)deg + 1.0f);
        row_off[g + 1] = bb + nIncl;
        if (g == 0) row_off[0] = 0;
    }
    cur[t] = nOff;
    __syncthreads();
    for (int j = t; j < nE; j += 256) {
        int2 e = eIn[j];
        int sl = atomicAdd(&cur[e.y & 255], 1);    // LDS cursor
        csr_src[bb + sl] = e.x;                    // scatter within 16KB region (L2-combined)
    }
}

// ---------- csr_norm[i] = dinv[src] * dinv[dst] (node-per-wave, lane-per-edge)
__global__ __launch_bounds__(256) void k_norm(const int* __restrict__ row_off,
                                              const int* __restrict__ csr_src,
                                              const float* __restrict__ dinv,
                                              float* __restrict__ csr_norm, int N) {
    int node = blockIdx.x * 4 + (threadIdx.x >> 6);
    int lane = threadIdx.x & 63;
    if (node >= N) return;
    int s = row_off[node], e = row_off[node + 1];
    float dd = dinv[node];
    for (int i = s + lane; i < e; i += 64)
        csr_norm[i] = dinv[csr_src[i]] * dd;
}

// ---------------- GEMM: [N,128] @ [128,128] -> [N,128], fp32 ----------------
__global__ __launch_bounds__(256) void k_gemm(const float* __restrict__ A,
                                              const float* __restrict__ W,
                                              float* __restrict__ O, int nrows) {
    __shared__ float sW[64 * 128];  // 32 KB
    __shared__ float sA[32 * 128];  // 16 KB
    int t = threadIdx.x;
    int row0 = blockIdx.x * 32;
    {
        int kc = t & 31, rq = t >> 5;
        float4* sA4 = (float4*)sA;
#pragma unroll
        for (int rr = 0; rr < 4; ++rr) {
            int r = rq + rr * 8;
            int gr = row0 + r;
            float4 v = make_float4(0.f, 0.f, 0.f, 0.f);
            if (gr < nrows) v = *(const float4*)(A + (size_t)gr * 128 + kc * 4);
            sA4[r * 32 + kc] = v;
        }
    }
    int c4 = (t & 31) * 4;
    int r4 = (t >> 5) * 4;
    float acc[4][4];
#pragma unroll
    for (int i = 0; i < 4; ++i)
#pragma unroll
        for (int j = 0; j < 4; ++j) acc[i][j] = 0.f;

    for (int half = 0; half < 2; ++half) {
        __syncthreads();
        {
            const float4* W4 = (const float4*)(W + half * 64 * 128);
            float4* sW4 = (float4*)sW;
#pragma unroll
            for (int i = 0; i < 8; ++i) sW4[t + 256 * i] = W4[t + 256 * i];
        }
        __syncthreads();
#pragma unroll 2
        for (int k = 0; k < 64; k += 4) {
            float4 w0 = *(const float4*)&sW[(k + 0) * 128 + c4];
            float4 w1 = *(const float4*)&sW[(k + 1) * 128 + c4];
            float4 w2 = *(const float4*)&sW[(k + 2) * 128 + c4];
            float4 w3 = *(const float4*)&sW[(k + 3) * 128 + c4];
#pragma unroll
            for (int i = 0; i < 4; ++i) {
                float4 a = *(const float4*)&sA[(r4 + i) * 128 + half * 64 + k];
                acc[i][0] = fmaf(a.x, w0.x, acc[i][0]);
                acc[i][1] = fmaf(a.x, w0.y, acc[i][1]);
                acc[i][2] = fmaf(a.x, w0.z, acc[i][2]);
                acc[i][3] = fmaf(a.x, w0.w, acc[i][3]);
                acc[i][0] = fmaf(a.y, w1.x, acc[i][0]);
                acc[i][1] = fmaf(a.y, w1.y, acc[i][1]);
                acc[i][2] = fmaf(a.y, w1.z, acc[i][2]);
                acc[i][3] = fmaf(a.y, w1.w, acc[i][3]);
                acc[i][0] = fmaf(a.z, w2.x, acc[i][0]);
                acc[i][1] = fmaf(a.z, w2.y, acc[i][1]);
                acc[i][2] = fmaf(a.z, w2.z, acc[i][2]);
                acc[i][3] = fmaf(a.z, w2.w, acc[i][3]);
                acc[i][0] = fmaf(a.w, w3.x, acc[i][0]);
                acc[i][1] = fmaf(a.w, w3.y, acc[i][1]);
                acc[i][2] = fmaf(a.w, w3.z, acc[i][2]);
                acc[i][3] = fmaf(a.w, w3.w, acc[i][3]);
            }
        }
    }
#pragma unroll
    for (int i = 0; i < 4; ++i) {
        int gr = row0 + r4 + i;
        if (gr < nrows) {
            float4 o;
            o.x = acc[i][0]; o.y = acc[i][1]; o.z = acc[i][2]; o.w = acc[i][3];
            *(float4*)(O + (size_t)gr * 128 + c4) = o;
        }
    }
}

// ---------------- aggregation: agg = sum norm*h[src] + dinv^2*h[self]; relu(+b)
__global__ __launch_bounds__(256) void k_agg(const float* __restrict__ h,
                                             const int* __restrict__ row_off,
                                             const int* __restrict__ csr_src,
                                             const float* __restrict__ csr_norm,
                                             const float* __restrict__ dinv,
                                             const float* __restrict__ bias,
                                             float* __restrict__ out, int n) {
    int node = blockIdx.x * 4 + (threadIdx.x >> 6);
    int lane = threadIdx.x & 63;
    if (node >= n) return;
    float d = dinv[node];
    float d2 = d * d;
    const float2* __restrict__ h2 = (const float2*)h;
    float2 self = h2[(size_t)node * 64 + lane];
    float acc0 = self.x * d2;
    float acc1 = self.y * d2;
    int s = row_off[node], e = row_off[node + 1];
    for (int t = s; t < e; t += 8) {
        int idx[8];
        float nm[8];
#pragma unroll
        for (int j = 0; j < 8; ++j) {
            int tt = t + j;
            bool ok = tt < e;
            int ts = ok ? tt : s;
            idx[j] = csr_src[ts];
            nm[j] = ok ? csr_norm[ts] : 0.f;
        }
        float2 v[8];
#pragma unroll
        for (int j = 0; j < 8; ++j) v[j] = h2[(size_t)idx[j] * 64 + lane];
#pragma unroll
        for (int j = 0; j < 8; ++j) {
            acc0 = fmaf(nm[j], v[j].x, acc0);
            acc1 = fmaf(nm[j], v[j].y, acc1);
        }
    }
    float2 b2 = ((const float2*)bias)[lane];
    float2 o;
    o.x = fmaxf(acc0 + b2.x, 0.f);
    o.y = fmaxf(acc1 + b2.y, 0.f);
    ((float2*)out)[(size_t)node * 64 + lane] = o;
}

// ---------------- pooling (batch sorted -> segment runs, few atomics) --------
__global__ void k_pool(const float* __restrict__ h, const int* __restrict__ batch,
                       float* __restrict__ gsum, float* __restrict__ gmax,
                       int* __restrict__ gcnt, int n) {
    int t = threadIdx.x;  // 128
    int start = blockIdx.x * 64;
    if (start >= n) return;
    int end = min(start + 64, n);
    int cur = batch[start];
    float s = 0.f, m = 0.f;
    int c = 0;
    for (int i = start; i < end; ++i) {
        int g = batch[i];
        if (g != cur) {
            atomicAdd(&gsum[cur * 128 + t], s);
            atomicMax((int*)&gmax[cur * 128 + t], __float_as_int(m));
            if (t == 0) atomicAdd(&gcnt[cur], c);
            s = 0.f; m = 0.f; c = 0; cur = g;
        }
        float v = h[(size_t)i * 128 + t];
        s += v;
        m = fmaxf(m, v);
        c++;
    }
    atomicAdd(&gsum[cur * 128 + t], s);
    atomicMax((int*)&gmax[cur * 128 + t], __float_as_int(m));
    if (t == 0) atomicAdd(&gcnt[cur], c);
}

// ---------------- MLP head, one block per graph ----------------
__global__ void k_head(const float* __restrict__ gsum, const float* __restrict__ gmax,
                       const int* __restrict__ gcnt, const float* __restrict__ Wc1,
                       const float* __restrict__ bc1, const float* __restrict__ Wc2,
                       const float* __restrict__ bc2, float* __restrict__ out, int G) {
    __shared__ float gv[256];
    __shared__ float hc[128];
    int g = blockIdx.x;
    if (g >= G) return;
    int t = threadIdx.x;  // 128
    float c = (float)gcnt[g];
    float inv = 1.0f / fmaxf(c, 1.0f);
    gv[t] = gsum[g * 128 + t] * inv;
    gv[128 + t] = gmax[g * 128 + t];
    __syncthreads();
    float a = bc1[t];
#pragma unroll 8
    for (int k = 0; k < 256; ++k) a = fmaf(gv[k], Wc1[k * 128 + t], a);
    hc[t] = fmaxf(a, 0.f);
    __syncthreads();
    if (t < 10) {
        float o = bc2[t];
        for (int k = 0; k < 128; ++k) o = fmaf(hc[k], Wc2[k * 10 + t], o);
        out[g * 10 + t] = o;
    }
}

extern "C" void kernel_launch(void* const* d_in, const int* in_sizes, int n_in,
                              void* d_out, int out_size, void* d_ws, size_t ws_size,
                              hipStream_t stream) {
    const float* x   = (const float*)d_in[0];
    const int*   ei  = (const int*)d_in[1];
    const int*   bat = (const int*)d_in[2];
    const float* W1  = (const float*)d_in[3];
    const float* b1  = (const float*)d_in[4];
    const float* W2  = (const float*)d_in[5];
    const float* b2  = (const float*)d_in[6];
    const float* W3  = (const float*)d_in[7];
    const float* b3  = (const float*)d_in[8];
    const float* Wc1 = (const float*)d_in[9];
    const float* bc1 = (const float*)d_in[10];
    const float* Wc2 = (const float*)d_in[11];
    const float* bc2 = (const float*)d_in[12];
    float* out = (float*)d_out;

    const int N = in_sizes[0] / HIDDIM;  // 100000
    const int E = in_sizes[1] / 2;       // 1600000
    const int G = out_size / 10;         // 512
    const int nbuck = (N + 255) >> 8;    // 391

    char* ws = (char*)d_ws;
    size_t off = 0;
    auto take = [&](size_t bytes) -> char* {
        char* p = ws + off;
        off += (bytes + 255) & ~(size_t)255;
        return p;
    };
    float* hA       = (float*)take((size_t)N * HIDDIM * 4);
    int2*  sortedA  = (int2*)hA;  // alias: sortedA (12.8MB) dead before hA first written
    float* hB       = (float*)take((size_t)N * HIDDIM * 4);
    float* dinv     = (float*)take((size_t)N * 4);
    int*   row_off  = (int*)take(((size_t)N + 1) * 4);
    int*   tableA   = (int*)take((size_t)(nbuck + 1) * NABLK * 4);
    int*   tot      = (int*)take(512 * 4);
    int*   bbase    = (int*)take(512 * 4);
    int*   csr_src  = (int*)take((size_t)E * 4);
    float* csr_norm = (float*)take((size_t)E * 4);
    float* gsum     = (float*)take((size_t)G * HIDDIM * 4);
    float* gmax     = (float*)take((size_t)G * HIDDIM * 4);
    int*   gcnt     = (int*)take((size_t)G * 4);

    hipMemsetAsync(gsum, 0, (size_t)G * HIDDIM * 4, stream);
    hipMemsetAsync(gmax, 0, (size_t)G * HIDDIM * 4, stream);
    hipMemsetAsync(gcnt, 0, (size_t)G * 4, stream);

    // CSR build: LDS counting sort (no global atomics)
    k_bucketA<<<NABLK, 1024, 0, stream>>>(ei, E, sortedA, tableA, nbuck);
    k_btot<<<nbuck, 256, 0, stream>>>(tableA, tot);
    k_bbase<<<1, 512, 0, stream>>>(tot, bbase, nbuck);
    k_bucketB<<<nbuck, 256, 0, stream>>>(sortedA, tableA, bbase, csr_src, row_off, dinv, N);
    k_norm<<<(N + 3) / 4, 256, 0, stream>>>(row_off, csr_src, dinv, csr_norm, N);

    int gb = (N + 31) / 32;
    int ab = (N + 3) / 4;
    k_gemm<<<gb, 256, 0, stream>>>(x, W1, hB, N);
    k_agg<<<ab, 256, 0, stream>>>(hB, row_off, csr_src, csr_norm, dinv, b1, hA, N);
    k_gemm<<<gb, 256, 0, stream>>>(hA, W2, hB, N);
    k_agg<<<ab, 256, 0, stream>>>(hB, row_off, csr_src, csr_norm, dinv, b2, hA, N);
    k_gemm<<<gb, 256, 0, stream>>>(hA, W3, hB, N);
    k_agg<<<ab, 256, 0, stream>>>(hB, row_off, csr_src, csr_norm, dinv, b3, hA, N);

    k_pool<<<(N + 63) / 64, 128, 0, stream>>>(hA, bat, gsum, gmax, gcnt, N);
    k_head<<<G, 128, 0, stream>>>(gsum, gmax, gcnt, Wc1, bc1, Wc2, bc2, out, G);
}